// Round 14
// baseline (2437.431 us; speedup 1.0000x reference)
//
#include <hip/hip_runtime.h>
#include <hip/hip_bf16.h>

#define B    256
#define S    192
#define F    64
#define HD   1024
#define PRED 48
#define TSTART (S - 1 - PRED)   // 143
#define NSLOT 48

typedef __attribute__((ext_vector_type(8))) short short8;
typedef __attribute__((ext_vector_type(4))) float f32x4;
typedef unsigned int u32;

static __device__ __forceinline__ short f2bf(float f) {
    __hip_bfloat16 h = __float2bfloat16(f);
    return *reinterpret_cast<short*>(&h);
}
static __device__ __forceinline__ f32x4 mfma16(short8 a, short8 b, f32x4 c) {
    return __builtin_amdgcn_mfma_f32_16x16x32_bf16(a, b, c, 0, 0, 0);
}
static __device__ __forceinline__ short8 ld8(const short* p) {
    return *reinterpret_cast<const short8*>(p);
}
// sc1 write-through store (MALL = device coherence point). R4-R13-proven.
// Readers: PLAIN cached loads on 48-slot-rotated fresh addresses.
static __device__ __forceinline__ void st_state(short* p, short v) {
    __hip_atomic_store(p, v, __ATOMIC_RELAXED, __HIP_MEMORY_SCOPE_AGENT);
}
static __device__ __forceinline__ u32 ld_flag(const u32* p) {
    return __hip_atomic_load(p, __ATOMIC_RELAXED, __HIP_MEMORY_SCOPE_AGENT);
}
static __device__ __forceinline__ void st_flag(u32* p, u32 v) {
    __hip_atomic_store(p, v, __ATOMIC_RELAXED, __HIP_MEMORY_SCOPE_AGENT);
}

// ---------------------------------------------------------------------------
// prep kernels (proven)
// ---------------------------------------------------------------------------
__global__ void fold_kernel(const float* __restrict__ Wh,
                            const float* __restrict__ Wih0,
                            float* __restrict__ Wfold) {
    const int n = (blockIdx.x & 3) * 256 + threadIdx.x;
    const int f = blockIdx.x >> 2;
    float a = 0.f;
#pragma unroll 16
    for (int k = 0; k < HD; ++k)
        a += Wh[f * HD + k] * Wih0[(size_t)k * HD + n];
    Wfold[f * HD + n] = a;
}

__global__ void bias_kernel(const float* __restrict__ bh,
                            const float* __restrict__ Wih0,
                            const float* __restrict__ bih,
                            const float* __restrict__ bhh,
                            float* __restrict__ bf0,
                            float* __restrict__ bf1) {
    __shared__ float red[256];
    const int nl = threadIdx.x & 15;
    const int kc = threadIdx.x >> 4;
    const int n  = blockIdx.x * 16 + nl;
    float a = 0.f;
#pragma unroll 8
    for (int k = kc * 64; k < kc * 64 + 64; ++k)
        a += bh[k] * Wih0[(size_t)k * HD + n];
    red[threadIdx.x] = a;
    __syncthreads();
    if (kc == 0) {
        float s = 0.f;
#pragma unroll
        for (int j = 0; j < 16; ++j) s += red[j * 16 + nl];
        bf0[n] = s + bih[n] + bhh[n];
        bf1[n] = bih[HD + n] + bhh[HD + n];
    }
}

__global__ void transpose_cast(const float* __restrict__ src,
                               short* __restrict__ dst, int K, int N) {
    __shared__ float tile[64][65];
    const int nk = K >> 6;
    const int bk = blockIdx.x % nk;
    const int bn = blockIdx.x / nk;
    const int i  = threadIdx.x;
    {
        const int c4 = (i & 15) * 4;
        for (int it = 0; it < 4; ++it) {
            const int k = (i >> 4) + it * 16;
            const float4 v = *reinterpret_cast<const float4*>(
                &src[(size_t)(bk * 64 + k) * N + bn * 64 + c4]);
            tile[k][c4 + 0] = v.x; tile[k][c4 + 1] = v.y;
            tile[k][c4 + 2] = v.z; tile[k][c4 + 3] = v.w;
        }
    }
    __syncthreads();
    {
        const int n  = i >> 2;
        const int kb = (i & 3) * 16;
        short* dp = &dst[(size_t)(bn * 64 + n) * K + bk * 64 + kb];
#pragma unroll
        for (int j = 0; j < 16; ++j) dp[j] = f2bf(tile[kb + j][n]);
    }
}

__global__ void xcast(const float* __restrict__ x, short* __restrict__ xb) {
    const size_t i = ((size_t)blockIdx.x * 256 + threadIdx.x) * 4;
    const float4 v = *reinterpret_cast<const float4*>(&x[i]);
    short4 o;
    o.x = f2bf(v.x); o.y = f2bf(v.y); o.z = f2bf(v.z); o.w = f2bf(v.w);
    *reinterpret_cast<short4*>(&xb[i]) = o;
}

// ---------------------------------------------------------------------------
// LDS layout (k-chunk-major, R11): addr = kc*2048 + r*64 + kg*16, 64KB/buffer.
// ---------------------------------------------------------------------------
static __device__ __forceinline__ void stage1(char* lds, const short* __restrict__ src,
                                              int row0) {
    const int tid = threadIdx.x;
#pragma unroll
    for (int it = 0; it < 8; ++it) {
        const int idx = it * 512 + tid;
        const int r   = (idx >> 2) & 31;
        const int off = ((idx >> 7) << 6) + ((idx & 3) << 4);
        const f32x4 v = *reinterpret_cast<const f32x4*>(
            (const char*)src + (size_t)(row0 + r) * 2048 + off);
        *reinterpret_cast<f32x4*>(lds + (idx << 4)) = v;
    }
}

// dual stage: h0 -> lds[0:64K), h1 -> lds[64K:128K); single latency exposure.
static __device__ __forceinline__ void stage2(char* lds,
                                              const short* __restrict__ s0,
                                              const short* __restrict__ s1,
                                              int row0) {
    const int tid = threadIdx.x;
#pragma unroll
    for (int it = 0; it < 8; ++it) {
        const int idx = it * 512 + tid;
        const int r   = (idx >> 2) & 31;
        const int off = ((idx >> 7) << 6) + ((idx & 3) << 4);
        const size_t g = (size_t)(row0 + r) * 2048 + off;
        const f32x4 a = *reinterpret_cast<const f32x4*>((const char*)s0 + g);
        const f32x4 b = *reinterpret_cast<const f32x4*>((const char*)s1 + g);
        *reinterpret_cast<f32x4*>(lds + (idx << 4)) = a;
        *reinterpret_cast<f32x4*>(lds + 65536 + (idx << 4)) = b;
    }
}

// gemmLG: 16x16 frag, K=1024; A from LDS, B from global (L2-resident weights)
// with 8-deep double-buffered prefetch (compile-time indices -> registers).
static __device__ __forceinline__ f32x4 gemmLG(const char* ldsA,
                                               const short* __restrict__ bp,
                                               f32x4 acc_in) {
    f32x4 acc0 = acc_in, acc1 = {0.f,0.f,0.f,0.f};
    short8 b0[8], b1[8];
#pragma unroll
    for (int j = 0; j < 8; ++j) b0[j] = ld8(bp + j * 32);
#pragma unroll
    for (int c = 0; c < 4; ++c) {
        if (c < 3) {
            short8* nxt = (c & 1) ? b0 : b1;
#pragma unroll
            for (int j = 0; j < 8; ++j) nxt[j] = ld8(bp + (c + 1) * 256 + j * 32);
        }
        const short8* cur = (c & 1) ? b1 : b0;
#pragma unroll
        for (int j = 0; j < 8; ++j) {
            const short8 a = *reinterpret_cast<const short8*>(
                ldsA + (c * 8 + j) * 2048);
            if (j & 1) acc1 = mfma16(a, cur[j], acc1);
            else       acc0 = mfma16(a, cur[j], acc0);
        }
    }
    return acc0 + acc1;
}

// ---------------------------------------------------------------------------
// Persistent skewed recurrence, per-group flag sync (R11-R13-proven protocol).
// 256 blocks x 512 thr, 128KB LDS.
// NEW (R14): XCD-locality bid mapping [T1, perf-only heuristic]. Default
// dispatch round-robins bid across XCDs (xcd = bid&7). Map
//   xcd   = bid & 7
//   layer = (bid>>3) & 1
//   ct    = xcd*2 + ((bid>>4)&1)       // ties weight col-slice to XCD
//   rt    = bid>>5
// -> per-XCD weight working set = 2x128KB (Whh0) + 2x256KB (Wih1+Whh1)
//    = 768KB << 4MB L2: weights L2-resident all 191 phases (vs 6MB thrash).
// Bijective bid->(layer,rt,ct); correctness independent of actual placement.
// ---------------------------------------------------------------------------
__global__ __launch_bounds__(512, 1) void rnn_pers(
    const short* __restrict__ xbf,
    const short* __restrict__ WfoldT, const float* __restrict__ bf0,
    const short* __restrict__ WhhT0, const short* __restrict__ WihT1,
    const short* __restrict__ WhhT1, const float* __restrict__ bf1,
    short* h0h, short* h1h, u32* flags0, u32* flags1) {

    extern __shared__ char lds[];                // 128 KB

    const int bid   = blockIdx.x;
    const int xcd   = bid & 7;
    const int layer = (bid >> 3) & 1;
    const int ct    = xcd * 2 + ((bid >> 4) & 1);   // 0..15
    const int rt    = bid >> 5;                     // 0..7
    const int w     = threadIdx.x >> 6;
    const int mh    = w & 1;
    const int nq    = w >> 1;
    const int l     = threadIdx.x & 63;
    const int lr    = l & 15, kg = l >> 4;
    const int row0  = rt * 32;
    const int m0    = row0 + mh * 16;
    const int n0    = ct * 64 + nq * 16;
    const int col   = n0 + lr;
    const int rb    = m0 + kg * 4;
    const char* ldsA = lds + mh * 1024 + lr * 64 + kg * 16;

    const float bb = (layer ? bf1 : bf0)[col];
    u32* myflag = (layer ? flags1 : flags0) + (rt * 16 + ct) * 32;
    const int tid = threadIdx.x;

    if (layer == 0) {
        const short* wf = WfoldT + (size_t)col * F + kg * 8;
        const short8 wf0 = ld8(wf), wf1 = ld8(wf + 32);   // loop-invariant
        for (int k = 0; k < S - 1; ++k) {
            // x-path loads issued before the poll (flag-independent)
            const short* xp = xbf + ((size_t)(m0 + lr) * S + k) * F + kg * 8;
            const short8 xa0 = ld8(xp);
            const short8 xa1 = ld8(xp + 32);
            if (k > 0) {
                __syncthreads();
                if (tid < 16) {
                    const u32* f = flags0 + (rt * 16 + tid) * 32;
                    while (ld_flag(f) < (u32)k) __builtin_amdgcn_s_sleep(1);
                } else if (tid < 32 && k >= 46) {
                    const u32* f = flags1 + (rt * 16 + (tid - 16)) * 32;
                    while (ld_flag(f) < (u32)(k - 45)) __builtin_amdgcn_s_sleep(1);
                }
                __syncthreads();
                stage1(lds, h0h + (size_t)((k - 1) % NSLOT) * B * HD, row0);
                __syncthreads();
            }
            f32x4 acc = {0.f, 0.f, 0.f, 0.f};
            acc = mfma16(xa0, wf0, acc);
            acc = mfma16(xa1, wf1, acc);
            if (k > 0)
                acc = gemmLG(ldsA, WhhT0 + (size_t)col * HD + kg * 8, acc);
            short* hd = h0h + (size_t)(k % NSLOT) * B * HD;
#pragma unroll
            for (int r = 0; r < 4; ++r)
                st_state(&hd[(size_t)(rb + r) * HD + col],
                         f2bf(tanhf(acc[r] + bb)));
            __syncthreads();                      // drain sc1 stores (vmcnt 0)
            if (tid == 0) st_flag(myflag, (u32)(k + 1));
        }
    } else {
        if (tid == 0) st_flag(myflag, 1u);        // phase 0: no-op
        for (int k = 1; k < S; ++k) {
            const int t = k - 1;
            __syncthreads();
            if (tid < 16) {
                const u32* f = flags0 + (rt * 16 + tid) * 32;
                while (ld_flag(f) < (u32)k) __builtin_amdgcn_s_sleep(1);
            } else if (tid < 32) {
                const u32* f = flags1 + (rt * 16 + (tid - 16)) * 32;
                while (ld_flag(f) < (u32)k) __builtin_amdgcn_s_sleep(1);
            }
            __syncthreads();
            const short* h0src = h0h + (size_t)((k - 1) % NSLOT) * B * HD;
            if (t > 0) {
                stage2(lds, h0src,
                       h1h + (size_t)((t - 1) % NSLOT) * B * HD, row0);
            } else {
                stage1(lds, h0src, row0);
            }
            __syncthreads();
            f32x4 acc = {0.f, 0.f, 0.f, 0.f};
            acc = gemmLG(ldsA, WihT1 + (size_t)col * HD + kg * 8, acc);
            if (t > 0)
                acc = gemmLG(ldsA + 65536, WhhT1 + (size_t)col * HD + kg * 8, acc);
#pragma unroll
            for (int r = 0; r < 4; ++r)
                st_state(&h1h[(size_t)(t % NSLOT) * B * HD
                              + (size_t)(rb + r) * HD + col],
                         f2bf(tanhf(acc[r] + bb)));
            __syncthreads();                      // drain sc1 stores
            if (tid == 0) st_flag(myflag, (u32)(k + 1));
        }
    }
}

// ---------------------------------------------------------------------------
// outgemm: out[b][p][f] = relu(h1(143+p)[b]) @ WoT + bo (history slots,
// bijective (143+p)%48). Kernel boundary gives coherence.
// ---------------------------------------------------------------------------
__global__ __launch_bounds__(256) void outgemm(
    const short* __restrict__ h1h, const short* __restrict__ WoT,
    const float* __restrict__ bo, float* __restrict__ out) {
    const int w = threadIdx.x >> 6, l = threadIdx.x & 63;
    const int lr = l & 15, kg = l >> 4;
    const int m0 = blockIdx.x * 64 + w * 16;
    const int arow = m0 + lr;                 // b*48+p
    const u32 bidx = (u32)arow / 48u;
    const u32 p    = (u32)arow % 48u;
    const u32 slot = (143u + p) % 48u;

    f32x4 acc[4] = {{0.f,0.f,0.f,0.f},{0.f,0.f,0.f,0.f},
                    {0.f,0.f,0.f,0.f},{0.f,0.f,0.f,0.f}};
    const short* ap = h1h + ((size_t)slot * B + bidx) * HD + kg * 8;
    const short* bp = WoT + (size_t)lr * HD + kg * 8;
#pragma unroll 4
    for (int k0 = 0; k0 < HD; k0 += 32) {
        short8 a = ld8(ap + k0);
#pragma unroll
        for (int j = 0; j < 8; ++j) a[j] = (a[j] < 0) ? (short)0 : a[j];  // relu
#pragma unroll
        for (int c = 0; c < 4; ++c)
            acc[c] = mfma16(a, ld8(bp + (size_t)c * 16 * HD + k0), acc[c]);
    }
    const int rb = m0 + kg * 4;
#pragma unroll
    for (int c = 0; c < 4; ++c) {
        const float bbv = bo[c * 16 + lr];
#pragma unroll
        for (int r = 0; r < 4; ++r)
            out[(size_t)(rb + r) * F + c * 16 + lr] = acc[c][r] + bbv;
    }
}

// ---------------------------------------------------------------------------
extern "C" void kernel_launch(void* const* d_in, const int* in_sizes, int n_in,
                              void* d_out, int out_size, void* d_ws, size_t ws_size,
                              hipStream_t stream) {
    const float* x   = (const float*)d_in[0];
    const float* Wh  = (const float*)d_in[1];
    const float* bh  = (const float*)d_in[2];
    const float* Wih = (const float*)d_in[3];
    const float* Whh = (const float*)d_in[4];
    const float* bih = (const float*)d_in[5];
    const float* bhh = (const float*)d_in[6];
    const float* Wo  = (const float*)d_in[7];
    const float* bo  = (const float*)d_in[8];
    float* out = (float*)d_out;

    char* p = (char*)d_ws;
    float* Wfold  = (float*)p; p += (size_t)F * HD * 4;
    float* bf0    = (float*)p; p += HD * 4;
    float* bf1    = (float*)p; p += HD * 4;
    short* WfoldT = (short*)p; p += (size_t)HD * F * 2;
    short* WhhT0  = (short*)p; p += (size_t)HD * HD * 2;
    short* WihT1  = (short*)p; p += (size_t)HD * HD * 2;
    short* WhhT1  = (short*)p; p += (size_t)HD * HD * 2;
    short* WoT    = (short*)p; p += (size_t)F * HD * 2;
    short* h0h    = (short*)p; p += (size_t)NSLOT * B * HD * 2;   // 24 MB
    short* h1h    = (short*)p; p += (size_t)NSLOT * B * HD * 2;   // 24 MB
    short* xbf    = (short*)p; p += (size_t)B * S * F * 2;
    u32*   sync   = (u32*)p;  p += 65536;
    // sync: flags0 = 128 flags x 128B (16KB) | flags1 at +16KB

    hipMemsetAsync(sync, 0, 65536, stream);

    fold_kernel<<<256, 256, 0, stream>>>(Wh, Wih, Wfold);
    bias_kernel<<<64, 256, 0, stream>>>(bh, Wih, bih, bhh, bf0, bf1);
    transpose_cast<<<16, 256, 0, stream>>>(Wfold, WfoldT, F, HD);
    transpose_cast<<<256, 256, 0, stream>>>(Whh, WhhT0, HD, HD);
    transpose_cast<<<256, 256, 0, stream>>>(Wih + (size_t)HD * HD, WihT1, HD, HD);
    transpose_cast<<<256, 256, 0, stream>>>(Whh + (size_t)HD * HD, WhhT1, HD, HD);
    transpose_cast<<<16, 256, 0, stream>>>(Wo, WoT, HD, F);
    xcast<<<(B * S * F) / (256 * 4), 256, 0, stream>>>(x, xbf);

    u32* flags0 = sync;
    u32* flags1 = sync + 4096;
    void* args[] = {
        (void*)&xbf, (void*)&WfoldT, (void*)&bf0, (void*)&WhhT0,
        (void*)&WihT1, (void*)&WhhT1, (void*)&bf1,
        (void*)&h0h, (void*)&h1h, (void*)&flags0, (void*)&flags1
    };
    hipLaunchCooperativeKernel((void*)rnn_pers, dim3(256), dim3(512),
                               args, 131072, stream);

    outgemm<<<192, 256, 0, stream>>>(h1h, WoT, bo, out);
}

// Round 15
// 2379.164 us; speedup vs baseline: 1.0245x; 1.0245x over previous
//
#include <hip/hip_runtime.h>
#include <hip/hip_bf16.h>

#define B    256
#define S    192
#define F    64
#define HD   1024
#define PRED 48
#define TSTART (S - 1 - PRED)   // 143
#define NSLOT 48

typedef __attribute__((ext_vector_type(8))) short short8;
typedef __attribute__((ext_vector_type(4))) float f32x4;
typedef unsigned int u32;

static __device__ __forceinline__ short f2bf(float f) {
    __hip_bfloat16 h = __float2bfloat16(f);
    return *reinterpret_cast<short*>(&h);
}
static __device__ __forceinline__ f32x4 mfma16(short8 a, short8 b, f32x4 c) {
    return __builtin_amdgcn_mfma_f32_16x16x32_bf16(a, b, c, 0, 0, 0);
}
static __device__ __forceinline__ short8 ld8(const short* p) {
    return *reinterpret_cast<const short8*>(p);
}
// sc1 write-through store (MALL = device coherence point). R4-R14-proven.
// Readers: PLAIN cached loads on 48-slot-rotated fresh addresses.
static __device__ __forceinline__ void st_state(short* p, short v) {
    __hip_atomic_store(p, v, __ATOMIC_RELAXED, __HIP_MEMORY_SCOPE_AGENT);
}
static __device__ __forceinline__ u32 ld_flag(const u32* p) {
    return __hip_atomic_load(p, __ATOMIC_RELAXED, __HIP_MEMORY_SCOPE_AGENT);
}
static __device__ __forceinline__ void st_flag(u32* p, u32 v) {
    __hip_atomic_store(p, v, __ATOMIC_RELAXED, __HIP_MEMORY_SCOPE_AGENT);
}

// ---------------------------------------------------------------------------
// prep kernels (proven)
// ---------------------------------------------------------------------------
__global__ void fold_kernel(const float* __restrict__ Wh,
                            const float* __restrict__ Wih0,
                            float* __restrict__ Wfold) {
    const int n = (blockIdx.x & 3) * 256 + threadIdx.x;
    const int f = blockIdx.x >> 2;
    float a = 0.f;
#pragma unroll 16
    for (int k = 0; k < HD; ++k)
        a += Wh[f * HD + k] * Wih0[(size_t)k * HD + n];
    Wfold[f * HD + n] = a;
}

__global__ void bias_kernel(const float* __restrict__ bh,
                            const float* __restrict__ Wih0,
                            const float* __restrict__ bih,
                            const float* __restrict__ bhh,
                            float* __restrict__ bf0,
                            float* __restrict__ bf1) {
    __shared__ float red[256];
    const int nl = threadIdx.x & 15;
    const int kc = threadIdx.x >> 4;
    const int n  = blockIdx.x * 16 + nl;
    float a = 0.f;
#pragma unroll 8
    for (int k = kc * 64; k < kc * 64 + 64; ++k)
        a += bh[k] * Wih0[(size_t)k * HD + n];
    red[threadIdx.x] = a;
    __syncthreads();
    if (kc == 0) {
        float s = 0.f;
#pragma unroll
        for (int j = 0; j < 16; ++j) s += red[j * 16 + nl];
        bf0[n] = s + bih[n] + bhh[n];
        bf1[n] = bih[HD + n] + bhh[HD + n];
    }
}

__global__ void transpose_cast(const float* __restrict__ src,
                               short* __restrict__ dst, int K, int N) {
    __shared__ float tile[64][65];
    const int nk = K >> 6;
    const int bk = blockIdx.x % nk;
    const int bn = blockIdx.x / nk;
    const int i  = threadIdx.x;
    {
        const int c4 = (i & 15) * 4;
        for (int it = 0; it < 4; ++it) {
            const int k = (i >> 4) + it * 16;
            const float4 v = *reinterpret_cast<const float4*>(
                &src[(size_t)(bk * 64 + k) * N + bn * 64 + c4]);
            tile[k][c4 + 0] = v.x; tile[k][c4 + 1] = v.y;
            tile[k][c4 + 2] = v.z; tile[k][c4 + 3] = v.w;
        }
    }
    __syncthreads();
    {
        const int n  = i >> 2;
        const int kb = (i & 3) * 16;
        short* dp = &dst[(size_t)(bn * 64 + n) * K + bk * 64 + kb];
#pragma unroll
        for (int j = 0; j < 16; ++j) dp[j] = f2bf(tile[kb + j][n]);
    }
}

__global__ void xcast(const float* __restrict__ x, short* __restrict__ xb) {
    const size_t i = ((size_t)blockIdx.x * 256 + threadIdx.x) * 4;
    const float4 v = *reinterpret_cast<const float4*>(&x[i]);
    short4 o;
    o.x = f2bf(v.x); o.y = f2bf(v.y); o.z = f2bf(v.z); o.w = f2bf(v.w);
    *reinterpret_cast<short4*>(&xb[i]) = o;
}

// ---------------------------------------------------------------------------
// LDS layout (k-chunk-major, R11): addr = kc*2048 + r*64 + kg*16, 64KB/buffer.
// ---------------------------------------------------------------------------
static __device__ __forceinline__ void stage1(char* lds, const short* __restrict__ src,
                                              int row0) {
    const int tid = threadIdx.x;
#pragma unroll
    for (int it = 0; it < 8; ++it) {
        const int idx = it * 512 + tid;
        const int r   = (idx >> 2) & 31;
        const int off = ((idx >> 7) << 6) + ((idx & 3) << 4);
        const f32x4 v = *reinterpret_cast<const f32x4*>(
            (const char*)src + (size_t)(row0 + r) * 2048 + off);
        *reinterpret_cast<f32x4*>(lds + (idx << 4)) = v;
    }
}

// dual stage: h0 -> lds[0:64K), h1 -> lds[64K:128K); single latency exposure.
static __device__ __forceinline__ void stage2(char* lds,
                                              const short* __restrict__ s0,
                                              const short* __restrict__ s1,
                                              int row0) {
    const int tid = threadIdx.x;
#pragma unroll
    for (int it = 0; it < 8; ++it) {
        const int idx = it * 512 + tid;
        const int r   = (idx >> 2) & 31;
        const int off = ((idx >> 7) << 6) + ((idx & 3) << 4);
        const size_t g = (size_t)(row0 + r) * 2048 + off;
        const f32x4 a = *reinterpret_cast<const f32x4*>((const char*)s0 + g);
        const f32x4 b = *reinterpret_cast<const f32x4*>((const char*)s1 + g);
        *reinterpret_cast<f32x4*>(lds + (idx << 4)) = a;
        *reinterpret_cast<f32x4*>(lds + 65536 + (idx << 4)) = b;
    }
}

// gemmLG: 16x16 frag, K=1024; A from LDS, B from global (L2-resident weights)
// with 8-deep double-buffered prefetch (compile-time indices -> registers).
static __device__ __forceinline__ f32x4 gemmLG(const char* ldsA,
                                               const short* __restrict__ bp,
                                               f32x4 acc_in) {
    f32x4 acc0 = acc_in, acc1 = {0.f,0.f,0.f,0.f};
    short8 b0[8], b1[8];
#pragma unroll
    for (int j = 0; j < 8; ++j) b0[j] = ld8(bp + j * 32);
#pragma unroll
    for (int c = 0; c < 4; ++c) {
        if (c < 3) {
            short8* nxt = (c & 1) ? b0 : b1;
#pragma unroll
            for (int j = 0; j < 8; ++j) nxt[j] = ld8(bp + (c + 1) * 256 + j * 32);
        }
        const short8* cur = (c & 1) ? b1 : b0;
#pragma unroll
        for (int j = 0; j < 8; ++j) {
            const short8 a = *reinterpret_cast<const short8*>(
                ldsA + (c * 8 + j) * 2048);
            if (j & 1) acc1 = mfma16(a, cur[j], acc1);
            else       acc0 = mfma16(a, cur[j], acc0);
        }
    }
    return acc0 + acc1;
}

// ---------------------------------------------------------------------------
// Persistent skewed recurrence, per-group flag sync (R11-R14-proven protocol).
// 256 blocks x 512 thr, 128KB LDS.
// R15 bid map [T1-style heuristic, correctness placement-free]: rt-locality.
//   xcd = bid&7 (default round-robin); u = bid>>3 (0..31 on each XCD)
//   layer = u&1
//   rt    = ((xcd&3)<<1) | ((u>>1)&1)     // each rt-group on only 2 XCDs
//   ct    = ((xcd>>2)<<3) | ((u>>2)&7)    // 8 fixed cts per XCD
// Per-XCD: weights = 8ct x (Whh0+Wih1+Whh1) slices = 3MB (L2-resident);
// state tiles read by 2 XCDs/group (was 8) and producer-local via
// write-through L2 copy -> state MALL fetch ~6x lower, staging off the
// MALL-latency path. Bijective bid->(layer,rt,ct); flags unchanged.
// ---------------------------------------------------------------------------
__global__ __launch_bounds__(512, 1) void rnn_pers(
    const short* __restrict__ xbf,
    const short* __restrict__ WfoldT, const float* __restrict__ bf0,
    const short* __restrict__ WhhT0, const short* __restrict__ WihT1,
    const short* __restrict__ WhhT1, const float* __restrict__ bf1,
    short* h0h, short* h1h, u32* flags0, u32* flags1) {

    extern __shared__ char lds[];                // 128 KB

    const int bid   = blockIdx.x;
    const int xcd   = bid & 7;
    const int u     = bid >> 3;                     // 0..31
    const int layer = u & 1;
    const int rt    = ((xcd & 3) << 1) | ((u >> 1) & 1);   // 0..7
    const int ct    = ((xcd >> 2) << 3) | ((u >> 2) & 7);  // 0..15
    const int w     = threadIdx.x >> 6;
    const int mh    = w & 1;
    const int nq    = w >> 1;
    const int l     = threadIdx.x & 63;
    const int lr    = l & 15, kg = l >> 4;
    const int row0  = rt * 32;
    const int m0    = row0 + mh * 16;
    const int n0    = ct * 64 + nq * 16;
    const int col   = n0 + lr;
    const int rb    = m0 + kg * 4;
    const char* ldsA = lds + mh * 1024 + lr * 64 + kg * 16;

    const float bb = (layer ? bf1 : bf0)[col];
    u32* myflag = (layer ? flags1 : flags0) + (rt * 16 + ct) * 32;
    const int tid = threadIdx.x;

    if (layer == 0) {
        const short* wf = WfoldT + (size_t)col * F + kg * 8;
        const short8 wf0 = ld8(wf), wf1 = ld8(wf + 32);   // loop-invariant
        for (int k = 0; k < S - 1; ++k) {
            // x-path loads issued before the poll (flag-independent)
            const short* xp = xbf + ((size_t)(m0 + lr) * S + k) * F + kg * 8;
            const short8 xa0 = ld8(xp);
            const short8 xa1 = ld8(xp + 32);
            if (k > 0) {
                __syncthreads();
                if (tid < 16) {
                    const u32* f = flags0 + (rt * 16 + tid) * 32;
                    while (ld_flag(f) < (u32)k) __builtin_amdgcn_s_sleep(1);
                } else if (tid < 32 && k >= 46) {
                    const u32* f = flags1 + (rt * 16 + (tid - 16)) * 32;
                    while (ld_flag(f) < (u32)(k - 45)) __builtin_amdgcn_s_sleep(1);
                }
                __syncthreads();
                stage1(lds, h0h + (size_t)((k - 1) % NSLOT) * B * HD, row0);
                __syncthreads();
            }
            f32x4 acc = {0.f, 0.f, 0.f, 0.f};
            acc = mfma16(xa0, wf0, acc);
            acc = mfma16(xa1, wf1, acc);
            if (k > 0)
                acc = gemmLG(ldsA, WhhT0 + (size_t)col * HD + kg * 8, acc);
            short* hd = h0h + (size_t)(k % NSLOT) * B * HD;
#pragma unroll
            for (int r = 0; r < 4; ++r)
                st_state(&hd[(size_t)(rb + r) * HD + col],
                         f2bf(tanhf(acc[r] + bb)));
            __syncthreads();                      // drain sc1 stores (vmcnt 0)
            if (tid == 0) st_flag(myflag, (u32)(k + 1));
        }
    } else {
        if (tid == 0) st_flag(myflag, 1u);        // phase 0: no-op
        for (int k = 1; k < S; ++k) {
            const int t = k - 1;
            __syncthreads();
            if (tid < 16) {
                const u32* f = flags0 + (rt * 16 + tid) * 32;
                while (ld_flag(f) < (u32)k) __builtin_amdgcn_s_sleep(1);
            } else if (tid < 32) {
                const u32* f = flags1 + (rt * 16 + (tid - 16)) * 32;
                while (ld_flag(f) < (u32)k) __builtin_amdgcn_s_sleep(1);
            }
            __syncthreads();
            const short* h0src = h0h + (size_t)((k - 1) % NSLOT) * B * HD;
            if (t > 0) {
                stage2(lds, h0src,
                       h1h + (size_t)((t - 1) % NSLOT) * B * HD, row0);
            } else {
                stage1(lds, h0src, row0);
            }
            __syncthreads();
            f32x4 acc = {0.f, 0.f, 0.f, 0.f};
            acc = gemmLG(ldsA, WihT1 + (size_t)col * HD + kg * 8, acc);
            if (t > 0)
                acc = gemmLG(ldsA + 65536, WhhT1 + (size_t)col * HD + kg * 8, acc);
#pragma unroll
            for (int r = 0; r < 4; ++r)
                st_state(&h1h[(size_t)(t % NSLOT) * B * HD
                              + (size_t)(rb + r) * HD + col],
                         f2bf(tanhf(acc[r] + bb)));
            __syncthreads();                      // drain sc1 stores
            if (tid == 0) st_flag(myflag, (u32)(k + 1));
        }
    }
}

// ---------------------------------------------------------------------------
// outgemm: out[b][p][f] = relu(h1(143+p)[b]) @ WoT + bo (history slots,
// bijective (143+p)%48). Kernel boundary gives coherence.
// ---------------------------------------------------------------------------
__global__ __launch_bounds__(256) void outgemm(
    const short* __restrict__ h1h, const short* __restrict__ WoT,
    const float* __restrict__ bo, float* __restrict__ out) {
    const int w = threadIdx.x >> 6, l = threadIdx.x & 63;
    const int lr = l & 15, kg = l >> 4;
    const int m0 = blockIdx.x * 64 + w * 16;
    const int arow = m0 + lr;                 // b*48+p
    const u32 bidx = (u32)arow / 48u;
    const u32 p    = (u32)arow % 48u;
    const u32 slot = (143u + p) % 48u;

    f32x4 acc[4] = {{0.f,0.f,0.f,0.f},{0.f,0.f,0.f,0.f},
                    {0.f,0.f,0.f,0.f},{0.f,0.f,0.f,0.f}};
    const short* ap = h1h + ((size_t)slot * B + bidx) * HD + kg * 8;
    const short* bp = WoT + (size_t)lr * HD + kg * 8;
#pragma unroll 4
    for (int k0 = 0; k0 < HD; k0 += 32) {
        short8 a = ld8(ap + k0);
#pragma unroll
        for (int j = 0; j < 8; ++j) a[j] = (a[j] < 0) ? (short)0 : a[j];  // relu
#pragma unroll
        for (int c = 0; c < 4; ++c)
            acc[c] = mfma16(a, ld8(bp + (size_t)c * 16 * HD + k0), acc[c]);
    }
    const int rb = m0 + kg * 4;
#pragma unroll
    for (int c = 0; c < 4; ++c) {
        const float bbv = bo[c * 16 + lr];
#pragma unroll
        for (int r = 0; r < 4; ++r)
            out[(size_t)(rb + r) * F + c * 16 + lr] = acc[c][r] + bbv;
    }
}

// ---------------------------------------------------------------------------
extern "C" void kernel_launch(void* const* d_in, const int* in_sizes, int n_in,
                              void* d_out, int out_size, void* d_ws, size_t ws_size,
                              hipStream_t stream) {
    const float* x   = (const float*)d_in[0];
    const float* Wh  = (const float*)d_in[1];
    const float* bh  = (const float*)d_in[2];
    const float* Wih = (const float*)d_in[3];
    const float* Whh = (const float*)d_in[4];
    const float* bih = (const float*)d_in[5];
    const float* bhh = (const float*)d_in[6];
    const float* Wo  = (const float*)d_in[7];
    const float* bo  = (const float*)d_in[8];
    float* out = (float*)d_out;

    char* p = (char*)d_ws;
    float* Wfold  = (float*)p; p += (size_t)F * HD * 4;
    float* bf0    = (float*)p; p += HD * 4;
    float* bf1    = (float*)p; p += HD * 4;
    short* WfoldT = (short*)p; p += (size_t)HD * F * 2;
    short* WhhT0  = (short*)p; p += (size_t)HD * HD * 2;
    short* WihT1  = (short*)p; p += (size_t)HD * HD * 2;
    short* WhhT1  = (short*)p; p += (size_t)HD * HD * 2;
    short* WoT    = (short*)p; p += (size_t)F * HD * 2;
    short* h0h    = (short*)p; p += (size_t)NSLOT * B * HD * 2;   // 24 MB
    short* h1h    = (short*)p; p += (size_t)NSLOT * B * HD * 2;   // 24 MB
    short* xbf    = (short*)p; p += (size_t)B * S * F * 2;
    u32*   sync   = (u32*)p;  p += 65536;
    // sync: flags0 = 128 flags x 128B (16KB) | flags1 at +16KB

    hipMemsetAsync(sync, 0, 65536, stream);

    fold_kernel<<<256, 256, 0, stream>>>(Wh, Wih, Wfold);
    bias_kernel<<<64, 256, 0, stream>>>(bh, Wih, bih, bhh, bf0, bf1);
    transpose_cast<<<16, 256, 0, stream>>>(Wfold, WfoldT, F, HD);
    transpose_cast<<<256, 256, 0, stream>>>(Whh, WhhT0, HD, HD);
    transpose_cast<<<256, 256, 0, stream>>>(Wih + (size_t)HD * HD, WihT1, HD, HD);
    transpose_cast<<<256, 256, 0, stream>>>(Whh + (size_t)HD * HD, WhhT1, HD, HD);
    transpose_cast<<<16, 256, 0, stream>>>(Wo, WoT, HD, F);
    xcast<<<(B * S * F) / (256 * 4), 256, 0, stream>>>(x, xbf);

    u32* flags0 = sync;
    u32* flags1 = sync + 4096;
    void* args[] = {
        (void*)&xbf, (void*)&WfoldT, (void*)&bf0, (void*)&WhhT0,
        (void*)&WihT1, (void*)&WhhT1, (void*)&bf1,
        (void*)&h0h, (void*)&h1h, (void*)&flags0, (void*)&flags1
    };
    hipLaunchCooperativeKernel((void*)rnn_pers, dim3(256), dim3(512),
                               args, 131072, stream);

    outgemm<<<192, 256, 0, stream>>>(h1h, WoT, bo, out);
}

// Round 16
// 2254.134 us; speedup vs baseline: 1.0813x; 1.0555x over previous
//
#include <hip/hip_runtime.h>
#include <hip/hip_bf16.h>

#define B    256
#define S    192
#define F    64
#define HD   1024
#define PRED 48
#define TSTART (S - 1 - PRED)   // 143
#define NSLOT 48

typedef __attribute__((ext_vector_type(8))) short short8;
typedef __attribute__((ext_vector_type(4))) float f32x4;
typedef unsigned int u32;

static __device__ __forceinline__ short f2bf(float f) {
    __hip_bfloat16 h = __float2bfloat16(f);
    return *reinterpret_cast<short*>(&h);
}
static __device__ __forceinline__ f32x4 mfma16(short8 a, short8 b, f32x4 c) {
    return __builtin_amdgcn_mfma_f32_16x16x32_bf16(a, b, c, 0, 0, 0);
}
static __device__ __forceinline__ short8 ld8(const short* p) {
    return *reinterpret_cast<const short8*>(p);
}
// sc1 write-through store (MALL = device coherence point). R4-R15-proven.
// Readers: PLAIN cached loads on 48-slot-rotated fresh addresses.
static __device__ __forceinline__ void st_state(short* p, short v) {
    __hip_atomic_store(p, v, __ATOMIC_RELAXED, __HIP_MEMORY_SCOPE_AGENT);
}
static __device__ __forceinline__ u32 ld_flag(const u32* p) {
    return __hip_atomic_load(p, __ATOMIC_RELAXED, __HIP_MEMORY_SCOPE_AGENT);
}
static __device__ __forceinline__ void st_flag(u32* p, u32 v) {
    __hip_atomic_store(p, v, __ATOMIC_RELAXED, __HIP_MEMORY_SCOPE_AGENT);
}

// ---------------------------------------------------------------------------
// prep kernels (proven)
// ---------------------------------------------------------------------------
__global__ void fold_kernel(const float* __restrict__ Wh,
                            const float* __restrict__ Wih0,
                            float* __restrict__ Wfold) {
    const int n = (blockIdx.x & 3) * 256 + threadIdx.x;
    const int f = blockIdx.x >> 2;
    float a = 0.f;
#pragma unroll 16
    for (int k = 0; k < HD; ++k)
        a += Wh[f * HD + k] * Wih0[(size_t)k * HD + n];
    Wfold[f * HD + n] = a;
}

__global__ void bias_kernel(const float* __restrict__ bh,
                            const float* __restrict__ Wih0,
                            const float* __restrict__ bih,
                            const float* __restrict__ bhh,
                            float* __restrict__ bf0,
                            float* __restrict__ bf1) {
    __shared__ float red[256];
    const int nl = threadIdx.x & 15;
    const int kc = threadIdx.x >> 4;
    const int n  = blockIdx.x * 16 + nl;
    float a = 0.f;
#pragma unroll 8
    for (int k = kc * 64; k < kc * 64 + 64; ++k)
        a += bh[k] * Wih0[(size_t)k * HD + n];
    red[threadIdx.x] = a;
    __syncthreads();
    if (kc == 0) {
        float s = 0.f;
#pragma unroll
        for (int j = 0; j < 16; ++j) s += red[j * 16 + nl];
        bf0[n] = s + bih[n] + bhh[n];
        bf1[n] = bih[HD + n] + bhh[HD + n];
    }
}

__global__ void transpose_cast(const float* __restrict__ src,
                               short* __restrict__ dst, int K, int N) {
    __shared__ float tile[64][65];
    const int nk = K >> 6;
    const int bk = blockIdx.x % nk;
    const int bn = blockIdx.x / nk;
    const int i  = threadIdx.x;
    {
        const int c4 = (i & 15) * 4;
        for (int it = 0; it < 4; ++it) {
            const int k = (i >> 4) + it * 16;
            const float4 v = *reinterpret_cast<const float4*>(
                &src[(size_t)(bk * 64 + k) * N + bn * 64 + c4]);
            tile[k][c4 + 0] = v.x; tile[k][c4 + 1] = v.y;
            tile[k][c4 + 2] = v.z; tile[k][c4 + 3] = v.w;
        }
    }
    __syncthreads();
    {
        const int n  = i >> 2;
        const int kb = (i & 3) * 16;
        short* dp = &dst[(size_t)(bn * 64 + n) * K + bk * 64 + kb];
#pragma unroll
        for (int j = 0; j < 16; ++j) dp[j] = f2bf(tile[kb + j][n]);
    }
}

__global__ void xcast(const float* __restrict__ x, short* __restrict__ xb) {
    const size_t i = ((size_t)blockIdx.x * 256 + threadIdx.x) * 4;
    const float4 v = *reinterpret_cast<const float4*>(&x[i]);
    short4 o;
    o.x = f2bf(v.x); o.y = f2bf(v.y); o.z = f2bf(v.z); o.w = f2bf(v.w);
    *reinterpret_cast<short4*>(&xb[i]) = o;
}

// ---------------------------------------------------------------------------
// LDS layout (k-chunk-major, R11): addr = kc*2048 + r*64 + kg*16, 64KB/buffer.
// ---------------------------------------------------------------------------
static __device__ __forceinline__ void stage1(char* lds, const short* __restrict__ src,
                                              int row0) {
    const int tid = threadIdx.x;
#pragma unroll
    for (int it = 0; it < 8; ++it) {
        const int idx = it * 512 + tid;
        const int r   = (idx >> 2) & 31;
        const int off = ((idx >> 7) << 6) + ((idx & 3) << 4);
        const f32x4 v = *reinterpret_cast<const f32x4*>(
            (const char*)src + (size_t)(row0 + r) * 2048 + off);
        *reinterpret_cast<f32x4*>(lds + (idx << 4)) = v;
    }
}

// gemmR: 16x16 frag, K=1024; A from LDS, B register-resident (wr[32], all
// indices compile-time -> stays in VGPRs, rule #20). No global B-stream.
static __device__ __forceinline__ f32x4 gemmR(const char* ldsA,
                                              const short8 (&wr)[32],
                                              f32x4 acc_in) {
    f32x4 acc0 = acc_in, acc1 = {0.f,0.f,0.f,0.f};
#pragma unroll
    for (int c = 0; c < 32; ++c) {
        const short8 a = *reinterpret_cast<const short8*>(ldsA + c * 2048);
        if (c & 1) acc1 = mfma16(a, wr[c], acc1);
        else       acc0 = mfma16(a, wr[c], acc0);
    }
    return acc0 + acc1;
}

// gemmLG4: streamed-B, 4-deep double-buffered prefetch (32 VGPR B in flight).
static __device__ __forceinline__ f32x4 gemmLG4(const char* ldsA,
                                                const short* __restrict__ bp,
                                                f32x4 acc_in) {
    f32x4 acc0 = acc_in, acc1 = {0.f,0.f,0.f,0.f};
    short8 b0[4], b1[4];
#pragma unroll
    for (int j = 0; j < 4; ++j) b0[j] = ld8(bp + j * 32);
#pragma unroll
    for (int c = 0; c < 8; ++c) {
        if (c < 7) {
            short8* nxt = (c & 1) ? b0 : b1;
#pragma unroll
            for (int j = 0; j < 4; ++j) nxt[j] = ld8(bp + (c + 1) * 128 + j * 32);
        }
        const short8* cur = (c & 1) ? b1 : b0;
#pragma unroll
        for (int j = 0; j < 4; ++j) {
            const short8 a = *reinterpret_cast<const short8*>(
                ldsA + (c * 4 + j) * 2048);
            if (j & 1) acc1 = mfma16(a, cur[j], acc1);
            else       acc0 = mfma16(a, cur[j], acc0);
        }
    }
    return acc0 + acc1;
}

// ---------------------------------------------------------------------------
// Persistent skewed recurrence (R15 map + flag protocol). R16 changes:
// (a) L1 pre-poll section = stage-h0 + gemm1(Wih1 streamed) — its input is
//     ready (L0 ~45 phases ahead); only stage-h1 + gemm2 stay post-poll.
// (b) Whh0/Whh1 column-slices register-resident (128 VGPR/thread, loaded
//     once) — post-poll gemm has no global B-stream.
// (c) Hbuf eliminated: outgemm reads h1 history slots directly (slots for
//     t>=143 are never overwritten: 191-143 < NSLOT).
// __launch_bounds__(512,2) pins <=256 VGPR (8 waves/CU preserved).
// ---------------------------------------------------------------------------
__global__ __launch_bounds__(512, 2) void rnn_pers(
    const short* __restrict__ xbf,
    const short* __restrict__ WfoldT, const float* __restrict__ bf0,
    const short* __restrict__ WhhT0, const short* __restrict__ WihT1,
    const short* __restrict__ WhhT1, const float* __restrict__ bf1,
    short* h0h, short* h1h, u32* flags0, u32* flags1) {

    extern __shared__ char lds[];                // 128 KB

    const int bid   = blockIdx.x;
    const int xcd   = bid & 7;
    const int u     = bid >> 3;
    const int layer = u & 1;
    const int rt    = ((xcd & 3) << 1) | ((u >> 1) & 1);   // 0..7
    const int ct    = ((xcd >> 2) << 3) | ((u >> 2) & 7);  // 0..15
    const int w     = threadIdx.x >> 6;
    const int mh    = w & 1;
    const int nq    = w >> 1;
    const int l     = threadIdx.x & 63;
    const int lr    = l & 15, kg = l >> 4;
    const int row0  = rt * 32;
    const int m0    = row0 + mh * 16;
    const int n0    = ct * 64 + nq * 16;
    const int col   = n0 + lr;
    const int rb    = m0 + kg * 4;
    const char* ldsA = lds + mh * 1024 + lr * 64 + kg * 16;

    const float bb = (layer ? bf1 : bf0)[col];
    u32* myflag = (layer ? flags1 : flags0) + (rt * 16 + ct) * 32;
    const int tid = threadIdx.x;

    // register-resident recurrent-weight slice (512B/thread = 128 VGPR)
    short8 wr[32];
    {
        const short* wp = (layer ? WhhT1 : WhhT0) + (size_t)col * HD + kg * 8;
#pragma unroll
        for (int c = 0; c < 32; ++c) wr[c] = ld8(wp + c * 32);
    }

    if (layer == 0) {
        const short* wf = WfoldT + (size_t)col * F + kg * 8;
        const short8 wf0 = ld8(wf), wf1 = ld8(wf + 32);
        for (int k = 0; k < S - 1; ++k) {
            const short* xp = xbf + ((size_t)(m0 + lr) * S + k) * F + kg * 8;
            const short8 xa0 = ld8(xp);
            const short8 xa1 = ld8(xp + 32);
            if (k > 0) {
                __syncthreads();
                if (tid < 16) {
                    const u32* f = flags0 + (rt * 16 + tid) * 32;
                    while (ld_flag(f) < (u32)k) __builtin_amdgcn_s_sleep(1);
                } else if (tid < 32 && k >= 46) {
                    const u32* f = flags1 + (rt * 16 + (tid - 16)) * 32;
                    while (ld_flag(f) < (u32)(k - 45)) __builtin_amdgcn_s_sleep(1);
                }
                __syncthreads();
                stage1(lds, h0h + (size_t)((k - 1) % NSLOT) * B * HD, row0);
                __syncthreads();
            }
            f32x4 acc = {0.f, 0.f, 0.f, 0.f};
            acc = mfma16(xa0, wf0, acc);
            acc = mfma16(xa1, wf1, acc);
            if (k > 0) acc = gemmR(ldsA, wr, acc);
            short* hd = h0h + (size_t)(k % NSLOT) * B * HD;
#pragma unroll
            for (int r = 0; r < 4; ++r)
                st_state(&hd[(size_t)(rb + r) * HD + col],
                         f2bf(tanhf(acc[r] + bb)));
            __syncthreads();                      // drain sc1 stores (vmcnt 0)
            if (tid == 0) st_flag(myflag, (u32)(k + 1));
        }
    } else {
        if (tid == 0) st_flag(myflag, 1u);
        char* ldsBbuf = lds + 65536;
        const char* ldsB = ldsBbuf + mh * 1024 + lr * 64 + kg * 16;
        for (int k = 1; k < S; ++k) {
            const int t = k - 1;
            // ---- pre-poll: h0 path (input long-ready; poll ~instant)
            __syncthreads();                      // prev-phase LDS reads done
            if (tid < 16) {
                const u32* f = flags0 + (rt * 16 + tid) * 32;
                while (ld_flag(f) < (u32)k) __builtin_amdgcn_s_sleep(1);
            }
            __syncthreads();
            stage1(lds, h0h + (size_t)((k - 1) % NSLOT) * B * HD, row0);
            __syncthreads();
            f32x4 acc = {0.f, 0.f, 0.f, 0.f};
            acc = gemmLG4(ldsA, WihT1 + (size_t)col * HD + kg * 8, acc);
            // ---- post-poll critical chain: h1 path, register-B gemm
            if (t > 0) {
                if (tid < 16) {
                    const u32* f = flags1 + (rt * 16 + tid) * 32;
                    while (ld_flag(f) < (u32)k) __builtin_amdgcn_s_sleep(1);
                }
                __syncthreads();
                stage1(ldsBbuf, h1h + (size_t)((t - 1) % NSLOT) * B * HD, row0);
                __syncthreads();
                acc = gemmR(ldsB, wr, acc);
            }
#pragma unroll
            for (int r = 0; r < 4; ++r)
                st_state(&h1h[(size_t)(t % NSLOT) * B * HD
                              + (size_t)(rb + r) * HD + col],
                         f2bf(tanhf(acc[r] + bb)));
            __syncthreads();                      // drain sc1 stores
            if (tid == 0) st_flag(myflag, (u32)(k + 1));
        }
    }
}

// ---------------------------------------------------------------------------
// outgemm: out[b][p][f] = relu(h1(143+p)[b]) @ WoT + bo (history slots,
// bijective (143+p)%48). Kernel boundary gives coherence.
// ---------------------------------------------------------------------------
__global__ __launch_bounds__(256) void outgemm(
    const short* __restrict__ h1h, const short* __restrict__ WoT,
    const float* __restrict__ bo, float* __restrict__ out) {
    const int w = threadIdx.x >> 6, l = threadIdx.x & 63;
    const int lr = l & 15, kg = l >> 4;
    const int m0 = blockIdx.x * 64 + w * 16;
    const int arow = m0 + lr;                 // b*48+p
    const u32 bidx = (u32)arow / 48u;
    const u32 p    = (u32)arow % 48u;
    const u32 slot = (143u + p) % 48u;

    f32x4 acc[4] = {{0.f,0.f,0.f,0.f},{0.f,0.f,0.f,0.f},
                    {0.f,0.f,0.f,0.f},{0.f,0.f,0.f,0.f}};
    const short* ap = h1h + ((size_t)slot * B + bidx) * HD + kg * 8;
    const short* bp = WoT + (size_t)lr * HD + kg * 8;
#pragma unroll 4
    for (int k0 = 0; k0 < HD; k0 += 32) {
        short8 a = ld8(ap + k0);
#pragma unroll
        for (int j = 0; j < 8; ++j) a[j] = (a[j] < 0) ? (short)0 : a[j];  // relu
#pragma unroll
        for (int c = 0; c < 4; ++c)
            acc[c] = mfma16(a, ld8(bp + (size_t)c * 16 * HD + k0), acc[c]);
    }
    const int rb = m0 + kg * 4;
#pragma unroll
    for (int c = 0; c < 4; ++c) {
        const float bbv = bo[c * 16 + lr];
#pragma unroll
        for (int r = 0; r < 4; ++r)
            out[(size_t)(rb + r) * F + c * 16 + lr] = acc[c][r] + bbv;
    }
}

// ---------------------------------------------------------------------------
extern "C" void kernel_launch(void* const* d_in, const int* in_sizes, int n_in,
                              void* d_out, int out_size, void* d_ws, size_t ws_size,
                              hipStream_t stream) {
    const float* x   = (const float*)d_in[0];
    const float* Wh  = (const float*)d_in[1];
    const float* bh  = (const float*)d_in[2];
    const float* Wih = (const float*)d_in[3];
    const float* Whh = (const float*)d_in[4];
    const float* bih = (const float*)d_in[5];
    const float* bhh = (const float*)d_in[6];
    const float* Wo  = (const float*)d_in[7];
    const float* bo  = (const float*)d_in[8];
    float* out = (float*)d_out;

    char* p = (char*)d_ws;
    float* Wfold  = (float*)p; p += (size_t)F * HD * 4;
    float* bf0    = (float*)p; p += HD * 4;
    float* bf1    = (float*)p; p += HD * 4;
    short* WfoldT = (short*)p; p += (size_t)HD * F * 2;
    short* WhhT0  = (short*)p; p += (size_t)HD * HD * 2;
    short* WihT1  = (short*)p; p += (size_t)HD * HD * 2;
    short* WhhT1  = (short*)p; p += (size_t)HD * HD * 2;
    short* WoT    = (short*)p; p += (size_t)F * HD * 2;
    short* h0h    = (short*)p; p += (size_t)NSLOT * B * HD * 2;   // 24 MB
    short* h1h    = (short*)p; p += (size_t)NSLOT * B * HD * 2;   // 24 MB
    short* xbf    = (short*)p; p += (size_t)B * S * F * 2;
    u32*   sync   = (u32*)p;  p += 65536;

    hipMemsetAsync(sync, 0, 65536, stream);

    fold_kernel<<<256, 256, 0, stream>>>(Wh, Wih, Wfold);
    bias_kernel<<<64, 256, 0, stream>>>(bh, Wih, bih, bhh, bf0, bf1);
    transpose_cast<<<16, 256, 0, stream>>>(Wfold, WfoldT, F, HD);
    transpose_cast<<<256, 256, 0, stream>>>(Whh, WhhT0, HD, HD);
    transpose_cast<<<256, 256, 0, stream>>>(Wih + (size_t)HD * HD, WihT1, HD, HD);
    transpose_cast<<<256, 256, 0, stream>>>(Whh + (size_t)HD * HD, WhhT1, HD, HD);
    transpose_cast<<<16, 256, 0, stream>>>(Wo, WoT, HD, F);
    xcast<<<(B * S * F) / (256 * 4), 256, 0, stream>>>(x, xbf);

    u32* flags0 = sync;
    u32* flags1 = sync + 4096;
    void* args[] = {
        (void*)&xbf, (void*)&WfoldT, (void*)&bf0, (void*)&WhhT0,
        (void*)&WihT1, (void*)&WhhT1, (void*)&bf1,
        (void*)&h0h, (void*)&h1h, (void*)&flags0, (void*)&flags1
    };
    hipLaunchCooperativeKernel((void*)rnn_pers, dim3(256), dim3(512),
                               args, 131072, stream);

    outgemm<<<192, 256, 0, stream>>>(h1h, WoT, bo, out);
}